// Round 7
// baseline (42.817 us; speedup 1.0000x reference)
//
#include <hip/hip_runtime.h>
#include <hip/hip_bf16.h>

typedef __bf16 bf16x8 __attribute__((ext_vector_type(8)));
typedef float f32x4 __attribute__((ext_vector_type(4)));

#define G 8
#define B 32
#define D 32
#define O 32
#define K 4096   // N*T (floats per W row)
#define T 64
#define BK 512                // floats staged per row per step (2KB burst)
#define NSTEP (K / BK)        // 8

// ws: [0, 256KB) XB bf16 [K/32][B][32]; then S f32 [2][G][D][O][B] (2MB)
#define XB_ELEMS (B * K)                // 131072 bf16 = 256 KB
#define S_ELEMS  (2 * G * D * O * B)    // 524288 f32  = 2 MB

// XB[kt][b][k5] = bf16(x[b][kt*32+k5])  -- MFMA B-fragment order, no mask.
__global__ __launch_bounds__(256) void prep_xb(const float* __restrict__ x,
                                               __bf16* __restrict__ xb) {
    int tid = blockIdx.x * 256 + threadIdx.x;   // 16384 threads, 8 elems each
    int kt = tid >> 7;
    int b  = (tid >> 2) & 31;
    int c  = tid & 3;
    int k  = kt * 32 + c * 8;
    const float4 x0 = *(const float4*)(x + b * K + k);
    const float4 x1 = *(const float4*)(x + b * K + k + 4);
    bf16x8 r;
    r[0] = (__bf16)x0.x; r[1] = (__bf16)x0.y; r[2] = (__bf16)x0.z; r[3] = (__bf16)x0.w;
    r[4] = (__bf16)x1.x; r[5] = (__bf16)x1.y; r[6] = (__bf16)x1.z; r[7] = (__bf16)x1.w;
    *(bf16x8*)(xb + (size_t)tid * 8) = r;   // flat idx == tid*8: coalesced
}

// Block (d,g): M = 32 contiguous o-rows, N = 32 b, full K. 512 threads = 8 waves.
// Wave w: output quadrant q=w&3 (bh=q&1, oh=q>>1), K-half h=w>>2; partials go to
// S slot h (summed by reduce_out). Each W row is owned start-to-finish by ONE
// block and advances in 2KB contiguous bursts (2 back-to-back 1KB gload_lds).
// XOR chunk-swizzle (row&7)<<4 on source AND lds-read addrs (rule 21).
// Pipeline: xb fragments register-prefetched 1 step ahead, issued BEFORE the
// stage loads, so vmcnt(16) retires exactly {cur stage + cur xb} and the 16
// younger prefetch loads stay in flight across the barrier (in-order retire).
__global__ __launch_bounds__(512) void gemm_main(const float* __restrict__ W,
                                                 const __bf16* __restrict__ xb,
                                                 const float* __restrict__ mask,
                                                 float* __restrict__ S) {
    __shared__ float ldsW[2][32 * BK];   // 2 x 64 KB
    const int d = blockIdx.x, g = blockIdx.y;
    const int wid  = threadIdx.x >> 6;
    const int lane = threadIdx.x & 63;
    const int q = wid & 3, h = wid >> 2;
    const int bh = q & 1, oh = q >> 1;
    const int l15 = lane & 15, g16 = lane >> 4;

    // A-fragment: row r (= o), within-row byte x = h*1024 + s*128 + g16*32,
    // LDS addr = r*2048 + (x ^ ((r&7)*16))  [swz bits < 128, chunk-safe]
    const int r = oh * 16 + l15;
    const int lds_ro = r * 2048 + h * 1024 + ((g16 * 32) ^ ((r & 7) * 16));

    // mask values this lane needs: t = (s&1)*32 + g16*8 + j  (h,step are %64==0)
    const float* mrow = mask + r * T + g16 * 8;
    const float4 me0 = *(const float4*)(mrow);
    const float4 me1 = *(const float4*)(mrow + 4);
    const float4 mo0 = *(const float4*)(mrow + 32);
    const float4 mo1 = *(const float4*)(mrow + 36);

    // XB base: k-tile kt = step*16 + h*8 + s; elem off = kt*1024 + b*32 + g16*8
    const __bf16* xbl = xb + (size_t)(h * 8) * 1024 + (bh * 16 + l15) * 32 + g16 * 8;

    // staging: wave wid owns rows o = 4*wid .. 4*wid+3
    const size_t wrow0 = ((size_t)(g * D + d) * O + 4 * wid) * K;

    f32x4 acc = {0.f, 0.f, 0.f, 0.f};

#define STAGE(buf, step)                                                          \
    {                                                                             \
        _Pragma("unroll")                                                         \
        for (int i = 0; i < 4; ++i) {                                             \
            const int row = 4 * wid + i;                                          \
            _Pragma("unroll")                                                     \
            for (int c = 0; c < 2; ++c) {                                         \
                const char* src = (const char*)(W + wrow0 + (size_t)i * K         \
                                                + (size_t)(step) * BK + c * 256)  \
                                  + ((lane * 16) ^ ((row & 7) * 16));             \
                __builtin_amdgcn_global_load_lds(                                 \
                    (const __attribute__((address_space(1))) void*)src,           \
                    (__attribute__((address_space(3))) void*)((char*)&ldsW[buf][0]\
                                                   + row * 2048 + c * 1024),      \
                    16, 0, 0);                                                    \
            }                                                                     \
        }                                                                         \
    }

    bf16x8 xr[2][8];
#define XLOAD(buf, step)                                                          \
    {                                                                             \
        _Pragma("unroll")                                                         \
        for (int s = 0; s < 8; ++s)                                               \
            xr[buf][s] = *(const bf16x8*)(xbl + (size_t)(step) * 16384            \
                                              + (size_t)s * 1024);                \
    }

    STAGE(0, 0);
    XLOAD(0, 0);

    #pragma unroll
    for (int step = 0; step < NSTEP; ++step) {
        const int cur = step & 1;
        if (step + 1 < NSTEP) {
            STAGE(cur ^ 1, step + 1);
            XLOAD(cur ^ 1, step + 1);
            __builtin_amdgcn_sched_barrier(0);
            // oldest 16 (= cur stage + cur xb) retired; 16 prefetch stay in flight
            asm volatile("s_waitcnt vmcnt(16)" ::: "memory");
        } else {
            __builtin_amdgcn_sched_barrier(0);
            asm volatile("s_waitcnt vmcnt(0)" ::: "memory");
        }
        __builtin_amdgcn_s_barrier();
        __builtin_amdgcn_sched_barrier(0);

        const char* lb = (const char*)&ldsW[cur][0];
        #pragma unroll
        for (int s = 0; s < 8; ++s) {
            const int a0 = lds_ro + s * 128;
            const f32x4 alo = *(const f32x4*)(lb + a0);
            const f32x4 ahi = *(const f32x4*)(lb + (a0 ^ 16));
            const float4 ms0 = (s & 1) ? mo0 : me0;
            const float4 ms1 = (s & 1) ? mo1 : me1;
            bf16x8 af;
            af[0] = (__bf16)(alo[0] * ms0.x); af[1] = (__bf16)(alo[1] * ms0.y);
            af[2] = (__bf16)(alo[2] * ms0.z); af[3] = (__bf16)(alo[3] * ms0.w);
            af[4] = (__bf16)(ahi[0] * ms1.x); af[5] = (__bf16)(ahi[1] * ms1.y);
            af[6] = (__bf16)(ahi[2] * ms1.z); af[7] = (__bf16)(ahi[3] * ms1.w);
            acc = __builtin_amdgcn_mfma_f32_16x16x32_bf16(af, xr[cur][s], acc, 0, 0, 0);
        }

        asm volatile("" ::: "memory");   // keep ds_reads above the barrier
        __builtin_amdgcn_s_barrier();    // all waves done reading buf[cur]
    }
#undef STAGE
#undef XLOAD

    // C/D: lane holds D[row=g16*4+i][col=l15]; rows = o (oh half), cols = b (bh half)
    float* Sp = S + (((size_t)(h * G + g) * D + d) * O + oh * 16) * B + bh * 16;
    #pragma unroll
    for (int i = 0; i < 4; ++i)
        Sp[(g16 * 4 + i) * B + l15] = acc[i];
}

// out[b][d][o] = bias[d][o] + sum_g y[b][g] * (S[0][g][d][o][b] + S[1][g][d][o][b])
__global__ __launch_bounds__(256) void reduce_out(const float* __restrict__ S,
                                                  const float* __restrict__ y,
                                                  const float* __restrict__ bias,
                                                  float* __restrict__ out) {
    int tid = blockIdx.x * 256 + threadIdx.x;   // 32768 = D*O*B
    int d = tid >> 10, o = (tid >> 5) & 31, b = tid & 31;
    float acc = bias[d * O + o];
    #pragma unroll
    for (int g = 0; g < G; ++g) {
        float s = S[(size_t)g * (D * O * B) + tid]
                + S[(size_t)(G + g) * (D * O * B) + tid];
        acc += y[b * G + g] * s;
    }
    out[b * (D * O) + d * O + o] = acc;
}

extern "C" void kernel_launch(void* const* d_in, const int* in_sizes, int n_in,
                              void* d_out, int out_size, void* d_ws, size_t ws_size,
                              hipStream_t stream) {
    const float* x    = (const float*)d_in[0];
    const float* y    = (const float*)d_in[1];
    const float* w    = (const float*)d_in[2];
    const float* bias = (const float*)d_in[3];
    const float* mask = (const float*)d_in[4];
    float* out = (float*)d_out;

    __bf16* xbp = (__bf16*)d_ws;
    float*  S   = (float*)((char*)d_ws + (size_t)XB_ELEMS * sizeof(__bf16));

    prep_xb<<<64, 256, 0, stream>>>(x, xbp);
    gemm_main<<<dim3(D, G), 512, 0, stream>>>(w, xbp, mask, S);
    reduce_out<<<128, 256, 0, stream>>>(S, y, bias, out);
}

// Round 8
// 35.158 us; speedup vs baseline: 1.2179x; 1.2179x over previous
//
#include <hip/hip_runtime.h>
#include <hip/hip_bf16.h>

typedef __bf16 bf16x8 __attribute__((ext_vector_type(8)));
typedef float f32x4 __attribute__((ext_vector_type(4)));

#define G 8
#define B 32
#define D 32
#define O 32
#define K 4096   // N*T (floats per W row)
#define T 64
#define KSPLIT 2
#define KCHUNK (K / KSPLIT)   // 2048 floats
#define BK 256                // floats staged per row per step (1KB burst)
#define NSTEP (KCHUNK / BK)   // 8
#define MROWS 16              // o-rows per block

// ws: XB bf16 [K/32][B][32] = 256 KB only.
#define XB_ELEMS (B * K)

// Fused prep: threads [0,16384) build XB (MFMA B-frag order, no mask);
// threads [16384, 49152) init out[b][d][o] = bias[d][o] (gemm atomically adds).
__global__ __launch_bounds__(256) void prep_and_init(const float* __restrict__ x,
                                                     const float* __restrict__ bias,
                                                     __bf16* __restrict__ xb,
                                                     float* __restrict__ out) {
    int tid = blockIdx.x * 256 + threadIdx.x;
    if (tid < 16384) {
        int b = (tid >> 2) & 31;
        int k = (tid >> 7) * 32 + (tid & 3) * 8;
        const float4 x0 = *(const float4*)(x + b * K + k);
        const float4 x1 = *(const float4*)(x + b * K + k + 4);
        bf16x8 r;
        r[0] = (__bf16)x0.x; r[1] = (__bf16)x0.y; r[2] = (__bf16)x0.z; r[3] = (__bf16)x0.w;
        r[4] = (__bf16)x1.x; r[5] = (__bf16)x1.y; r[6] = (__bf16)x1.z; r[7] = (__bf16)x1.w;
        *(bf16x8*)(xb + (size_t)tid * 8) = r;   // flat idx == tid*8: coalesced
    } else {
        int t2 = tid - 16384;           // 32768 = B*D*O, out flat = b*1024 + d*32 + o
        out[t2] = bias[t2 & 1023];
    }
}

// Block (d, g, oh, ks): M = 16 contiguous o-rows, N = 32 b, K-half ks.
// 128 threads = 2 waves; wave bh covers b in [16*bh, 16*bh+16).
// W staged via global_load_lds, 1KB contiguous burst per o-row per step;
// XOR chunk-swizzle (row&7)<<4 on source AND lds-read addrs (rule 21).
// mask[o][t] applied to the A-fragment before bf16 convert.
// 32KB LDS/block -> 4 independent blocks/CU for barrier-latency hiding.
// Epilogue: out[b][d][o] += y[b][g] * acc  (unsafeAtomicAdd, 16 adders/elem).
__global__ __launch_bounds__(128) void gemm_main(const float* __restrict__ W,
                                                 const __bf16* __restrict__ xb,
                                                 const float* __restrict__ mask,
                                                 const float* __restrict__ y,
                                                 float* __restrict__ out) {
    __shared__ float ldsW[2][MROWS * BK];   // 2 x 16 KB
    const int d = blockIdx.x, g = blockIdx.y;
    const int oh = blockIdx.z & 1, ks = blockIdx.z >> 1;
    const int wid  = threadIdx.x >> 6;      // 0..1 = bh
    const int lane = threadIdx.x & 63;
    const int bh = wid;
    const int l15 = lane & 15, g16 = lane >> 4;

    // A-fragment: local row = l15, within-row byte = s*128 + g16*32 (+16 hi), swizzled
    const int lds_ro = l15 * 1024 + ((g16 * 32) ^ ((l15 & 7) * 16));

    // mask row o = oh*16 + l15; lane needs t = (s&1)*32 + g16*8 + j
    const float* mrow = mask + (oh * 16 + l15) * T + g16 * 8;
    const float4 me0 = *(const float4*)(mrow);
    const float4 me1 = *(const float4*)(mrow + 4);
    const float4 mo0 = *(const float4*)(mrow + 32);
    const float4 mo1 = *(const float4*)(mrow + 36);

    // XB: k-tile kt = ks*64 + step*8 + s; elem = kt*1024 + b*32 + g16*8
    const __bf16* xbl = xb + (size_t)(ks * (KCHUNK / 32)) * 1024
                           + (bh * 16 + l15) * 32 + g16 * 8;

    // staging: wave wid stages local rows 8*wid .. 8*wid+7
    const size_t wrow0 = ((size_t)(g * D + d) * O + oh * 16 + 8 * wid) * K
                         + (size_t)ks * KCHUNK;

    f32x4 acc = {0.f, 0.f, 0.f, 0.f};

#define STAGE(buf, step)                                                          \
    {                                                                             \
        _Pragma("unroll")                                                         \
        for (int i = 0; i < 8; ++i) {                                             \
            const int row = 8 * wid + i;                                          \
            const char* src = (const char*)(W + wrow0 + (size_t)i * K             \
                                            + (size_t)(step) * BK)                \
                              + ((lane * 16) ^ (i * 16));                         \
            __builtin_amdgcn_global_load_lds(                                     \
                (const __attribute__((address_space(1))) void*)src,               \
                (__attribute__((address_space(3))) void*)((char*)&ldsW[buf][0]    \
                                                          + row * 1024),          \
                16, 0, 0);                                                        \
        }                                                                         \
    }

    STAGE(0, 0);
    __syncthreads();

    int cur = 0;
    for (int step = 0; step < NSTEP; ++step) {
        if (step + 1 < NSTEP) STAGE(cur ^ 1, step + 1);

        const char* lb = (const char*)&ldsW[cur][0];
        const __bf16* xs = xbl + (size_t)(step * 8) * 1024;
        #pragma unroll
        for (int s = 0; s < 8; ++s) {
            const int a0 = lds_ro + s * 128;
            const f32x4 alo = *(const f32x4*)(lb + a0);
            const f32x4 ahi = *(const f32x4*)(lb + (a0 ^ 16));
            const float4 ms0 = (s & 1) ? mo0 : me0;
            const float4 ms1 = (s & 1) ? mo1 : me1;
            bf16x8 af;
            af[0] = (__bf16)(alo[0] * ms0.x); af[1] = (__bf16)(alo[1] * ms0.y);
            af[2] = (__bf16)(alo[2] * ms0.z); af[3] = (__bf16)(alo[3] * ms0.w);
            af[4] = (__bf16)(ahi[0] * ms1.x); af[5] = (__bf16)(ahi[1] * ms1.y);
            af[6] = (__bf16)(ahi[2] * ms1.z); af[7] = (__bf16)(ahi[3] * ms1.w);
            const bf16x8 bfr = *(const bf16x8*)(xs + (size_t)s * 1024);
            acc = __builtin_amdgcn_mfma_f32_16x16x32_bf16(af, bfr, acc, 0, 0, 0);
        }
        __syncthreads();
        cur ^= 1;
    }
#undef STAGE

    // C/D: lane holds D[row=g16*4+i][col=l15]; row = o-in-tile, col = b-in-tile
    const int bg = bh * 16 + l15;                 // global b
    const float yv = y[bg * G + g];
    float* op = out + bg * (D * O) + d * O + oh * 16;
    #pragma unroll
    for (int i = 0; i < 4; ++i)
        unsafeAtomicAdd(op + g16 * 4 + i, yv * acc[i]);
}

extern "C" void kernel_launch(void* const* d_in, const int* in_sizes, int n_in,
                              void* d_out, int out_size, void* d_ws, size_t ws_size,
                              hipStream_t stream) {
    const float* x    = (const float*)d_in[0];
    const float* y    = (const float*)d_in[1];
    const float* w    = (const float*)d_in[2];
    const float* bias = (const float*)d_in[3];
    const float* mask = (const float*)d_in[4];
    float* out = (float*)d_out;

    __bf16* xbp = (__bf16*)d_ws;

    prep_and_init<<<192, 256, 0, stream>>>(x, bias, xbp, out);
    gemm_main<<<dim3(D, G, 4), 128, 0, stream>>>(w, xbp, mask, y, out);
}